// Round 1
// baseline (216.889 us; speedup 1.0000x reference)
//
#include <hip/hip_runtime.h>
#include <math.h>

#define NWIRES 6
#define DIM 64
#define NTOK 32768            // B*T = 16*2048
#define TPB_SIM 256
#define NCHUNK 8
#define CHUNKLEN (2048 / NCHUNK)
#define SQRT6F 2.4494897427831781f

// ---------------------------------------------------------------------------
// Kernel 0: precompute cos/sin of half-angles for all 3 circuits (3 x 18 gates)
// layout: cs[circ*36 + g*2 + 0] = cos(theta_g/2), +1 = sin(theta_g/2)
// g = 0..5 RX layer, 6..11 RY layer, 12..17 final RY layer (matches params rows)
// ---------------------------------------------------------------------------
__global__ void qsa_prep(const float* __restrict__ pq,
                         const float* __restrict__ pk,
                         const float* __restrict__ pv,
                         float* __restrict__ cs) {
    int i = threadIdx.x;
    if (i >= 54) return;
    int circ = i / 18, g = i % 18;
    const float* p = (circ == 0) ? pq : (circ == 1 ? pk : pv);
    float s, c;
    sincosf(0.5f * p[g], &s, &c);
    cs[i * 2 + 0] = c;
    cs[i * 2 + 1] = s;
}

// ---------------------------------------------------------------------------
// Gate helpers: state held entirely in registers, fully unrolled, all indices
// compile-time constants. Wire j <-> bit position (5-j), mask M = 32>>j.
// ---------------------------------------------------------------------------
template<int M>
__device__ __forceinline__ void rx_g(float* re, float* im, float c, float s) {
#pragma unroll
    for (int i = 0; i < DIM; ++i) {
        if (i & M) continue;
        int j = i | M;
        float r0 = re[i], i0 = im[i], r1 = re[j], i1 = im[j];
        // RX: a0' = c*a0 - i s*a1 ; a1' = -i s*a0 + c*a1
        re[i] = c * r0 + s * i1;
        im[i] = c * i0 - s * r1;
        re[j] = c * r1 + s * i0;
        im[j] = c * i1 - s * r0;
    }
}

template<int M>
__device__ __forceinline__ void ry_g(float* re, float* im, float c, float s) {
#pragma unroll
    for (int i = 0; i < DIM; ++i) {
        if (i & M) continue;
        int j = i | M;
        float r0 = re[i], i0 = im[i], r1 = re[j], i1 = im[j];
        // RY: a0' = c*a0 - s*a1 ; a1' = s*a0 + c*a1
        re[i] = c * r0 - s * r1;
        im[i] = c * i0 - s * i1;
        re[j] = c * r1 + s * r0;
        im[j] = c * i1 + s * i0;
    }
}

template<int MC, int MT>
__device__ __forceinline__ void cnot_g(float* re, float* im) {
    // control bit set -> swap target pair; pure register rename after unroll
#pragma unroll
    for (int i = 0; i < DIM; ++i) {
        if (!(i & MC) || (i & MT)) continue;
        int j = i | MT;
        float tr = re[i]; re[i] = re[j]; re[j] = tr;
        float ti = im[i]; im[i] = im[j]; im[j] = ti;
    }
}

// ---------------------------------------------------------------------------
// Kernel 1: simulate one circuit (blockIdx.y in {q,k,v}) for one token/thread.
// State unnormalized (unitary evolution preserves norm); divide by norm2 at end.
// Outputs: zq[t] = sqrt(6)*<Z0>_q ; kv[t*8] = <Z0>_k ; kv[t*8+1..6] = <Z_w>_v
// ---------------------------------------------------------------------------
__global__ void qsa_sim(const float* __restrict__ x,
                        const float* __restrict__ cs,
                        float* __restrict__ zq,
                        float* __restrict__ kv) {
    int token = blockIdx.x * TPB_SIM + threadIdx.x;
    int circ = blockIdx.y;
    const float* P = cs + circ * 36;

    float re[DIM], im[DIM];
    const float4* xp4 = (const float4*)(x + (size_t)token * DIM);
#pragma unroll
    for (int k = 0; k < DIM / 4; ++k) {
        float4 v = xp4[k];
        re[4*k+0] = v.x; re[4*k+1] = v.y; re[4*k+2] = v.z; re[4*k+3] = v.w;
        im[4*k+0] = 0.f; im[4*k+1] = 0.f; im[4*k+2] = 0.f; im[4*k+3] = 0.f;
    }

    // per-wire RX then RY (wires commute across j; order within wire preserved)
    rx_g<32>(re, im, P[0],  P[1]);  ry_g<32>(re, im, P[12], P[13]);
    rx_g<16>(re, im, P[2],  P[3]);  ry_g<16>(re, im, P[14], P[15]);
    rx_g< 8>(re, im, P[4],  P[5]);  ry_g< 8>(re, im, P[16], P[17]);
    rx_g< 4>(re, im, P[6],  P[7]);  ry_g< 4>(re, im, P[18], P[19]);
    rx_g< 2>(re, im, P[8],  P[9]);  ry_g< 2>(re, im, P[20], P[21]);
    rx_g< 1>(re, im, P[10], P[11]); ry_g< 1>(re, im, P[22], P[23]);
    // CNOT ring (0,1)..(4,5),(5,0); wire j -> mask 32>>j
    cnot_g<32,16>(re, im);
    cnot_g<16, 8>(re, im);
    cnot_g< 8, 4>(re, im);
    cnot_g< 4, 2>(re, im);
    cnot_g< 2, 1>(re, im);
    cnot_g< 1,32>(re, im);
    // final RY layer
    ry_g<32>(re, im, P[24], P[25]);
    ry_g<16>(re, im, P[26], P[27]);
    ry_g< 8>(re, im, P[28], P[29]);
    ry_g< 4>(re, im, P[30], P[31]);
    ry_g< 2>(re, im, P[32], P[33]);
    ry_g< 1>(re, im, P[34], P[35]);

    // <Z_w> = (2*S_w - norm2)/norm2 where S_w = sum of |amp|^2 with bit(5-w)==0
    float norm2 = 0.f, s0=0.f, s1=0.f, s2=0.f, s3=0.f, s4=0.f, s5=0.f;
#pragma unroll
    for (int i = 0; i < DIM; ++i) {
        float p = re[i]*re[i] + im[i]*im[i];
        norm2 += p;
        if (!(i & 32)) s0 += p;
        if (!(i & 16)) s1 += p;
        if (!(i &  8)) s2 += p;
        if (!(i &  4)) s3 += p;
        if (!(i &  2)) s4 += p;
        if (!(i &  1)) s5 += p;
    }
    float inv = 1.0f / norm2;
    if (circ == 0) {
        zq[token] = SQRT6F * (2.f*s0 - norm2) * inv;   // pre-scale by sqrt(6)
    } else if (circ == 1) {
        kv[(size_t)token * 8 + 0] = (2.f*s0 - norm2) * inv;
    } else {
        float* o = kv + (size_t)token * 8;
        o[1] = (2.f*s0 - norm2) * inv;
        o[2] = (2.f*s1 - norm2) * inv;
        o[3] = (2.f*s2 - norm2) * inv;
        o[4] = (2.f*s3 - norm2) * inv;
        o[5] = (2.f*s4 - norm2) * inv;
        o[6] = (2.f*s5 - norm2) * inv;
        o[7] = 0.f;
    }
}

// ---------------------------------------------------------------------------
// Kernel 2: rank-1 streaming softmax-attention, partial over an s-chunk.
// logit(t,s) = a_t * zk_s with |logit| <= sqrt(6) -> no max subtraction needed.
// kv reads are wave-uniform (address depends only on blockIdx) -> scalar loads.
// ---------------------------------------------------------------------------
__global__ __launch_bounds__(64) void qsa_attn_partial(
        const float* __restrict__ zq,
        const float* __restrict__ kv,
        float* __restrict__ part) {
    int t = blockIdx.x * 64 + threadIdx.x;   // 512 t-tiles of 64
    int b = blockIdx.x >> 5;                 // 32 tiles per batch (2048/64)
    int c = blockIdx.y;                      // s-chunk
    const float* base = kv + ((size_t)(b * 2048 + c * CHUNKLEN)) * 8;
    float a = zq[t];
    float den = 0.f, a0 = 0.f, a1 = 0.f, a2 = 0.f, a3 = 0.f, a4 = 0.f, a5 = 0.f;
#pragma unroll 4
    for (int j = 0; j < CHUNKLEN; ++j) {
        const float* e = base + (size_t)j * 8;
        float w = __expf(a * e[0]);
        den += w;
        a0 += w * e[1]; a1 += w * e[2]; a2 += w * e[3];
        a3 += w * e[4]; a4 += w * e[5]; a5 += w * e[6];
    }
    float* o = part + ((size_t)t * NCHUNK + c) * 8;
    o[0] = den; o[1] = a0; o[2] = a1; o[3] = a2;
    o[4] = a3;  o[5] = a4; o[6] = a5; o[7] = 0.f;
}

// ---------------------------------------------------------------------------
// Kernel 3: combine s-chunk partials, normalize, store (B,T,6) fp32 output.
// ---------------------------------------------------------------------------
__global__ void qsa_attn_reduce(const float* __restrict__ part,
                                float* __restrict__ out) {
    int t = blockIdx.x * 256 + threadIdx.x;
    const float4* p4 = (const float4*)(part + (size_t)t * NCHUNK * 8);
    float den = 0.f, a0 = 0.f, a1 = 0.f, a2 = 0.f, a3 = 0.f, a4 = 0.f, a5 = 0.f;
#pragma unroll
    for (int c = 0; c < NCHUNK; ++c) {
        float4 q0 = p4[2*c], q1 = p4[2*c+1];
        den += q0.x; a0 += q0.y; a1 += q0.z; a2 += q0.w;
        a3 += q1.x;  a4 += q1.y; a5 += q1.z;
    }
    float inv = 1.0f / den;
    float* o = out + (size_t)t * 6;
    o[0] = a0*inv; o[1] = a1*inv; o[2] = a2*inv;
    o[3] = a3*inv; o[4] = a4*inv; o[5] = a5*inv;
}

// ---------------------------------------------------------------------------
extern "C" void kernel_launch(void* const* d_in, const int* in_sizes, int n_in,
                              void* d_out, int out_size, void* d_ws, size_t ws_size,
                              hipStream_t stream) {
    const float* x  = (const float*)d_in[0];
    const float* pq = (const float*)d_in[1];
    const float* pk = (const float*)d_in[2];
    const float* pv = (const float*)d_in[3];
    float* w = (float*)d_ws;
    // workspace layout (floats): cs[128] | zq[32768] | kv[32768*8] | part[32768*8*8]
    float* cs   = w;
    float* zq   = w + 128;
    float* kv   = w + 128 + NTOK;
    float* part = w + 128 + NTOK + NTOK * 8;
    float* out  = (float*)d_out;

    qsa_prep<<<1, 64, 0, stream>>>(pq, pk, pv, cs);
    qsa_sim<<<dim3(NTOK / TPB_SIM, 3), TPB_SIM, 0, stream>>>(x, cs, zq, kv);
    qsa_attn_partial<<<dim3(NTOK / 64, NCHUNK), 64, 0, stream>>>(zq, kv, part);
    qsa_attn_reduce<<<NTOK / 256, 256, 0, stream>>>(part, out);
}

// Round 2
// 134.515 us; speedup vs baseline: 1.6124x; 1.6124x over previous
//
#include <hip/hip_runtime.h>
#include <math.h>

#define NWIRES 6
#define DIM 64
#define NTOK 32768            // B*T = 16*2048
#define NCHUNK 8
#define CHUNKLEN (2048 / NCHUNK)
#define SQRT6F 2.4494897427831781f
#define LOG2EF 1.44269504088896f

// ---------------------------------------------------------------------------
// Kernel 0: precompute cos/sin of half-angles for all 3 circuits (3 x 18 gates)
// layout: cs[circ*36 + g*2 + 0] = cos(theta_g/2), +1 = sin(theta_g/2)
// ---------------------------------------------------------------------------
__global__ void qsa_prep(const float* __restrict__ pq,
                         const float* __restrict__ pk,
                         const float* __restrict__ pv,
                         float* __restrict__ cs) {
    int i = threadIdx.x;
    if (i >= 54) return;
    int circ = i / 18, g = i % 18;
    const float* p = (circ == 0) ? pq : (circ == 1 ? pk : pv);
    float s, c;
    sincosf(0.5f * p[g], &s, &c);
    cs[i * 2 + 0] = c;
    cs[i * 2 + 1] = s;
}

// ---------------------------------------------------------------------------
// Gate helpers: state fully in registers, fully unrolled, compile-time indices.
// Wire j <-> bit position (5-j), mask M = 32>>j.
// ---------------------------------------------------------------------------
template<int M>
__device__ __forceinline__ void rx_g(float* re, float* im, float c, float s) {
#pragma unroll
    for (int i = 0; i < DIM; ++i) {
        if (i & M) continue;
        int j = i | M;
        float r0 = re[i], i0 = im[i], r1 = re[j], i1 = im[j];
        re[i] = c * r0 + s * i1;
        im[i] = c * i0 - s * r1;
        re[j] = c * r1 + s * i0;
        im[j] = c * i1 - s * r0;
    }
}

template<int M>
__device__ __forceinline__ void ry_g(float* re, float* im, float c, float s) {
#pragma unroll
    for (int i = 0; i < DIM; ++i) {
        if (i & M) continue;
        int j = i | M;
        float r0 = re[i], i0 = im[i], r1 = re[j], i1 = im[j];
        re[i] = c * r0 - s * r1;
        im[i] = c * i0 - s * i1;
        re[j] = c * r1 + s * r0;
        im[j] = c * i1 + s * i0;
    }
}

template<int MC, int MT>
__device__ __forceinline__ void cnot_g(float* re, float* im) {
#pragma unroll
    for (int i = 0; i < DIM; ++i) {
        if (!(i & MC) || (i & MT)) continue;
        int j = i | MT;
        float tr = re[i]; re[i] = re[j]; re[j] = tr;
        float ti = im[i]; im[i] = im[j]; im[j] = ti;
    }
}

// ---------------------------------------------------------------------------
// Kernel 1: one token/thread, one circuit per blockIdx.y in {q,k,v}.
// __launch_bounds__(64,2): VGPR cap 256 so the 128-float state stays in
// registers (R1 post-mortem: default cap=64 VGPR spilled ~400MB to scratch).
// ---------------------------------------------------------------------------
__global__ __launch_bounds__(64, 2) void qsa_sim(
        const float* __restrict__ x,
        const float* __restrict__ cs,
        float* __restrict__ zq,
        float* __restrict__ kv) {
    int token = blockIdx.x * 64 + threadIdx.x;
    int circ = blockIdx.y;
    const float* P = cs + circ * 36;

    float re[DIM], im[DIM];
    const float4* xp4 = (const float4*)(x + (size_t)token * DIM);
#pragma unroll
    for (int k = 0; k < DIM / 4; ++k) {
        float4 v = xp4[k];
        re[4*k+0] = v.x; re[4*k+1] = v.y; re[4*k+2] = v.z; re[4*k+3] = v.w;
        im[4*k+0] = 0.f; im[4*k+1] = 0.f; im[4*k+2] = 0.f; im[4*k+3] = 0.f;
    }

    rx_g<32>(re, im, P[0],  P[1]);  ry_g<32>(re, im, P[12], P[13]);
    rx_g<16>(re, im, P[2],  P[3]);  ry_g<16>(re, im, P[14], P[15]);
    rx_g< 8>(re, im, P[4],  P[5]);  ry_g< 8>(re, im, P[16], P[17]);
    rx_g< 4>(re, im, P[6],  P[7]);  ry_g< 4>(re, im, P[18], P[19]);
    rx_g< 2>(re, im, P[8],  P[9]);  ry_g< 2>(re, im, P[20], P[21]);
    rx_g< 1>(re, im, P[10], P[11]); ry_g< 1>(re, im, P[22], P[23]);
    cnot_g<32,16>(re, im);
    cnot_g<16, 8>(re, im);
    cnot_g< 8, 4>(re, im);
    cnot_g< 4, 2>(re, im);
    cnot_g< 2, 1>(re, im);
    cnot_g< 1,32>(re, im);
    ry_g<32>(re, im, P[24], P[25]);
    ry_g<16>(re, im, P[26], P[27]);
    ry_g< 8>(re, im, P[28], P[29]);
    ry_g< 4>(re, im, P[30], P[31]);
    ry_g< 2>(re, im, P[32], P[33]);
    ry_g< 1>(re, im, P[34], P[35]);

    // <Z_w> = (2*S_w - norm2)/norm2, S_w = sum |amp|^2 over bit(5-w)==0
    float norm2 = 0.f, s0=0.f, s1=0.f, s2=0.f, s3=0.f, s4=0.f, s5=0.f;
#pragma unroll
    for (int i = 0; i < DIM; ++i) {
        float p = re[i]*re[i] + im[i]*im[i];
        norm2 += p;
        if (!(i & 32)) s0 += p;
        if (!(i & 16)) s1 += p;
        if (!(i &  8)) s2 += p;
        if (!(i &  4)) s3 += p;
        if (!(i &  2)) s4 += p;
        if (!(i &  1)) s5 += p;
    }
    float inv = 1.0f / norm2;
    if (circ == 0) {
        zq[token] = SQRT6F * (2.f*s0 - norm2) * inv;   // pre-scaled by sqrt(6)
    } else if (circ == 1) {
        kv[(size_t)token * 8 + 0] = (2.f*s0 - norm2) * inv;
    } else {
        float* o = kv + (size_t)token * 8;
        o[1] = (2.f*s0 - norm2) * inv;
        o[2] = (2.f*s1 - norm2) * inv;
        o[3] = (2.f*s2 - norm2) * inv;
        o[4] = (2.f*s3 - norm2) * inv;
        o[5] = (2.f*s4 - norm2) * inv;
        o[6] = (2.f*s5 - norm2) * inv;
        o[7] = 0.f;
    }
}

// ---------------------------------------------------------------------------
// Kernel 2: rank-1 streaming softmax partial over an s-chunk.
// Stage the 8KB kv chunk into LDS (coalesced float4), then wave-uniform
// ds_read_b128 broadcasts per s-entry. |logit| <= sqrt(6) -> no max-sub.
// log2(e) folded into the query scalar -> bare v_exp_f32.
// ---------------------------------------------------------------------------
__global__ __launch_bounds__(64) void qsa_attn_partial(
        const float* __restrict__ zq,
        const float* __restrict__ kv,
        float* __restrict__ part) {
    __shared__ float4 sk[CHUNKLEN * 2];   // 256 entries x 32B = 8KB
    int lane = threadIdx.x;
    int tile = blockIdx.x;                // 512 t-tiles of 64
    int c = blockIdx.y;                   // s-chunk
    int b = tile >> 5;                    // 32 tiles per batch
    const float4* src = (const float4*)(kv + ((size_t)(b * 2048 + c * CHUNKLEN)) * 8);
#pragma unroll
    for (int r = 0; r < (CHUNKLEN * 2) / 64; ++r)   // 8 float4 per lane
        sk[r * 64 + lane] = src[r * 64 + lane];
    __syncthreads();

    int t = tile * 64 + lane;
    float a = zq[t] * LOG2EF;             // exp(a*z) = exp2((a*log2e)*z)
    float den = 0.f, a0 = 0.f, a1 = 0.f, a2 = 0.f, a3 = 0.f, a4 = 0.f, a5 = 0.f;
#pragma unroll 4
    for (int j = 0; j < CHUNKLEN; ++j) {
        float4 e0 = sk[2*j], e1 = sk[2*j + 1];
        float w = exp2f(a * e0.x);
        den += w;
        a0 += w * e0.y; a1 += w * e0.z; a2 += w * e0.w;
        a3 += w * e1.x; a4 += w * e1.y; a5 += w * e1.z;
    }
    float* o = part + ((size_t)t * NCHUNK + c) * 8;
    o[0] = den; o[1] = a0; o[2] = a1; o[3] = a2;
    o[4] = a3;  o[5] = a4; o[6] = a5; o[7] = 0.f;
}

// ---------------------------------------------------------------------------
// Kernel 3: combine s-chunk partials, normalize, store (B,T,6) fp32 output.
// ---------------------------------------------------------------------------
__global__ void qsa_attn_reduce(const float* __restrict__ part,
                                float* __restrict__ out) {
    int t = blockIdx.x * 256 + threadIdx.x;
    const float4* p4 = (const float4*)(part + (size_t)t * NCHUNK * 8);
    float den = 0.f, a0 = 0.f, a1 = 0.f, a2 = 0.f, a3 = 0.f, a4 = 0.f, a5 = 0.f;
#pragma unroll
    for (int c = 0; c < NCHUNK; ++c) {
        float4 q0 = p4[2*c], q1 = p4[2*c+1];
        den += q0.x; a0 += q0.y; a1 += q0.z; a2 += q0.w;
        a3 += q1.x;  a4 += q1.y; a5 += q1.z;
    }
    float inv = 1.0f / den;
    float* o = out + (size_t)t * 6;
    o[0] = a0*inv; o[1] = a1*inv; o[2] = a2*inv;
    o[3] = a3*inv; o[4] = a4*inv; o[5] = a5*inv;
}

// ---------------------------------------------------------------------------
extern "C" void kernel_launch(void* const* d_in, const int* in_sizes, int n_in,
                              void* d_out, int out_size, void* d_ws, size_t ws_size,
                              hipStream_t stream) {
    const float* x  = (const float*)d_in[0];
    const float* pq = (const float*)d_in[1];
    const float* pk = (const float*)d_in[2];
    const float* pv = (const float*)d_in[3];
    float* w = (float*)d_ws;
    // workspace (floats): cs[128] | zq[32768] | kv[32768*8] | part[32768*8*8]
    float* cs   = w;
    float* zq   = w + 128;
    float* kv   = w + 128 + NTOK;
    float* part = w + 128 + NTOK + NTOK * 8;
    float* out  = (float*)d_out;

    qsa_prep<<<1, 64, 0, stream>>>(pq, pk, pv, cs);
    qsa_sim<<<dim3(NTOK / 64, 3), 64, 0, stream>>>(x, cs, zq, kv);
    qsa_attn_partial<<<dim3(NTOK / 64, NCHUNK), 64, 0, stream>>>(zq, kv, part);
    qsa_attn_reduce<<<NTOK / 256, 256, 0, stream>>>(part, out);
}

// Round 3
// 97.205 us; speedup vs baseline: 2.2312x; 1.3838x over previous
//
#include <hip/hip_runtime.h>
#include <math.h>

#define NWIRES 6
#define DIM 64
#define NTOK 32768            // B*T = 16*2048
#define NBATCH 16
#define TPB 2048              // tokens per batch
#define NMOM 16               // Taylor order: exp(az), |az|<=sqrt(6); rem ~8e-8
#define SQRT6F 2.4494897427831781f

// ---------------------------------------------------------------------------
// Kernel 0: cos/sin of half-angles, 3 circuits x 18 gates.
// cs[circ*36 + g*2 + {0,1}] = {cos,sin}(theta_g/2); g: 0..5 RX, 6..11 RY0, 12..17 RY1
// ---------------------------------------------------------------------------
__global__ void qsa_prep(const float* __restrict__ pq,
                         const float* __restrict__ pk,
                         const float* __restrict__ pv,
                         float* __restrict__ cs) {
    int i = threadIdx.x;
    if (i >= 54) return;
    int circ = i / 18, g = i % 18;
    const float* p = (circ == 0) ? pq : (circ == 1 ? pk : pv);
    float s, c;
    sincosf(0.5f * p[g], &s, &c);
    cs[i * 2 + 0] = c;
    cs[i * 2 + 1] = s;
}

// ---------------------------------------------------------------------------
// Gate helpers: state fully in registers, fully unrolled, compile-time indices.
// Wire j <-> bit (5-j), mask M = 32>>j.
// ---------------------------------------------------------------------------
template<int M>
__device__ __forceinline__ void rx_g(float* re, float* im, float c, float s) {
#pragma unroll
    for (int i = 0; i < DIM; ++i) {
        if (i & M) continue;
        int j = i | M;
        float r0 = re[i], i0 = im[i], r1 = re[j], i1 = im[j];
        re[i] = c * r0 + s * i1;
        im[i] = c * i0 - s * r1;
        re[j] = c * r1 + s * i0;
        im[j] = c * i1 - s * r0;
    }
}

template<int M>
__device__ __forceinline__ void ry_g(float* re, float* im, float c, float s) {
#pragma unroll
    for (int i = 0; i < DIM; ++i) {
        if (i & M) continue;
        int j = i | M;
        float r0 = re[i], i0 = im[i], r1 = re[j], i1 = im[j];
        re[i] = c * r0 - s * r1;
        im[i] = c * i0 - s * i1;
        re[j] = c * r1 + s * r0;
        im[j] = c * i1 + s * i0;
    }
}

template<int MC, int MT>
__device__ __forceinline__ void cnot_g(float* re, float* im) {
#pragma unroll
    for (int i = 0; i < DIM; ++i) {
        if (!(i & MC) || (i & MT)) continue;
        int j = i | MT;
        float tr = re[i]; re[i] = re[j]; re[j] = tr;
        float ti = im[i]; im[i] = im[j]; im[j] = ti;
    }
}

// ---------------------------------------------------------------------------
// Kernel 1: one token/thread, one circuit per blockIdx.y.
// waves_per_eu(1,1): occupancy target pinned to 1 wave/EU -> 512-VGPR budget,
// no pressure spilling (R2 post-mortem: (64,2) still settled at 128 VGPR and
// spilled ~42 MB scratch).
// ---------------------------------------------------------------------------
__global__ __attribute__((amdgpu_waves_per_eu(1, 1)))
__launch_bounds__(64) void qsa_sim(
        const float* __restrict__ x,
        const float* __restrict__ cs,
        float* __restrict__ zq,
        float* __restrict__ kv) {
    int token = blockIdx.x * 64 + threadIdx.x;
    int circ = blockIdx.y;
    const float* P = cs + circ * 36;

    float re[DIM], im[DIM];
    const float4* xp4 = (const float4*)(x + (size_t)token * DIM);
#pragma unroll
    for (int k = 0; k < DIM / 4; ++k) {
        float4 v = xp4[k];
        re[4*k+0] = v.x; re[4*k+1] = v.y; re[4*k+2] = v.z; re[4*k+3] = v.w;
        im[4*k+0] = 0.f; im[4*k+1] = 0.f; im[4*k+2] = 0.f; im[4*k+3] = 0.f;
    }

    rx_g<32>(re, im, P[0],  P[1]);  ry_g<32>(re, im, P[12], P[13]);
    rx_g<16>(re, im, P[2],  P[3]);  ry_g<16>(re, im, P[14], P[15]);
    rx_g< 8>(re, im, P[4],  P[5]);  ry_g< 8>(re, im, P[16], P[17]);
    rx_g< 4>(re, im, P[6],  P[7]);  ry_g< 4>(re, im, P[18], P[19]);
    rx_g< 2>(re, im, P[8],  P[9]);  ry_g< 2>(re, im, P[20], P[21]);
    rx_g< 1>(re, im, P[10], P[11]); ry_g< 1>(re, im, P[22], P[23]);
    cnot_g<32,16>(re, im);
    cnot_g<16, 8>(re, im);
    cnot_g< 8, 4>(re, im);
    cnot_g< 4, 2>(re, im);
    cnot_g< 2, 1>(re, im);
    cnot_g< 1,32>(re, im);
    ry_g<32>(re, im, P[24], P[25]);
    ry_g<16>(re, im, P[26], P[27]);
    ry_g< 8>(re, im, P[28], P[29]);
    ry_g< 4>(re, im, P[30], P[31]);
    ry_g< 2>(re, im, P[32], P[33]);
    ry_g< 1>(re, im, P[34], P[35]);

    float norm2 = 0.f, s0=0.f, s1=0.f, s2=0.f, s3=0.f, s4=0.f, s5=0.f;
#pragma unroll
    for (int i = 0; i < DIM; ++i) {
        float p = re[i]*re[i] + im[i]*im[i];
        norm2 += p;
        if (!(i & 32)) s0 += p;
        if (!(i & 16)) s1 += p;
        if (!(i &  8)) s2 += p;
        if (!(i &  4)) s3 += p;
        if (!(i &  2)) s4 += p;
        if (!(i &  1)) s5 += p;
    }
    float inv = 1.0f / norm2;
    if (circ == 0) {
        zq[token] = SQRT6F * (2.f*s0 - norm2) * inv;   // a_t, natural-exp scale
    } else if (circ == 1) {
        kv[(size_t)token * 8 + 0] = (2.f*s0 - norm2) * inv;
    } else {
        float* o = kv + (size_t)token * 8;
        o[1] = (2.f*s0 - norm2) * inv;
        o[2] = (2.f*s1 - norm2) * inv;
        o[3] = (2.f*s2 - norm2) * inv;
        o[4] = (2.f*s3 - norm2) * inv;
        o[5] = (2.f*s4 - norm2) * inv;
        o[6] = (2.f*s5 - norm2) * inv;
        o[7] = 0.f;
    }
}

// ---------------------------------------------------------------------------
// Kernel 2: partial power moments per (batch, chunk-of-256).
// S_m = sum z^m, H_{m,w} = sum z^m * v_w, m=0..15.  112 register accumulators,
// butterfly-reduced across the wave; lane 0 stores 112 floats.
// ---------------------------------------------------------------------------
__global__ __attribute__((amdgpu_waves_per_eu(1, 2)))
__launch_bounds__(64) void qsa_moments_partial(
        const float* __restrict__ kv,
        float* __restrict__ mpart) {
    int blk = blockIdx.x;             // 16 batches * 8 chunks
    int b = blk >> 3, c = blk & 7;
    int lane = threadIdx.x;
    float S[NMOM], H[NMOM][6];
#pragma unroll
    for (int m = 0; m < NMOM; ++m) {
        S[m] = 0.f;
#pragma unroll
        for (int w = 0; w < 6; ++w) H[m][w] = 0.f;
    }
    const float* base = kv + ((size_t)(b * TPB + c * 256)) * 8;
#pragma unroll
    for (int r = 0; r < 4; ++r) {
        const float4* e = (const float4*)(base + (size_t)(r * 64 + lane) * 8);
        float4 e0 = e[0], e1 = e[1];
        float z = e0.x;
        float v0 = e0.y, v1 = e0.z, v2 = e0.w, v3 = e1.x, v4 = e1.y, v5 = e1.z;
        float p = 1.f;
#pragma unroll
        for (int m = 0; m < NMOM; ++m) {
            S[m] += p;
            H[m][0] += p * v0; H[m][1] += p * v1; H[m][2] += p * v2;
            H[m][3] += p * v3; H[m][4] += p * v4; H[m][5] += p * v5;
            p *= z;
        }
    }
#pragma unroll
    for (int d = 32; d >= 1; d >>= 1) {
#pragma unroll
        for (int m = 0; m < NMOM; ++m) {
            S[m] += __shfl_xor(S[m], d, 64);
#pragma unroll
            for (int w = 0; w < 6; ++w) H[m][w] += __shfl_xor(H[m][w], d, 64);
        }
    }
    if (lane == 0) {
        float* o = mpart + (size_t)blk * 112;
#pragma unroll
        for (int m = 0; m < NMOM; ++m) {
            float* om = o + m * 7;
            om[0] = S[m];
            om[1] = H[m][0]; om[2] = H[m][1]; om[3] = H[m][2];
            om[4] = H[m][3]; om[5] = H[m][4]; om[6] = H[m][5];
        }
    }
}

// ---------------------------------------------------------------------------
// Kernel 3: combine 8 chunk-partials -> mom[16][112]. 1792 = 256*7 outputs.
// ---------------------------------------------------------------------------
__global__ void qsa_moments_combine(const float* __restrict__ mpart,
                                    float* __restrict__ mom) {
#pragma unroll
    for (int it = 0; it < 7; ++it) {
        int i = it * 256 + threadIdx.x;       // i in [0, 1792)
        int b = i / 112, j = i % 112;
        float s = 0.f;
#pragma unroll
        for (int c = 0; c < 8; ++c) s += mpart[(size_t)(b * 8 + c) * 112 + j];
        mom[(size_t)b * 112 + j] = s;
    }
}

// ---------------------------------------------------------------------------
// Kernel 4: per-token evaluation. den = sum_m p_m S_m, out_w = sum_m p_m H_mw
// with p_m = a^m/m!.  Moment loads are block-uniform -> scalar loads.
// ---------------------------------------------------------------------------
__global__ __launch_bounds__(256) void qsa_eval(
        const float* __restrict__ zq,
        const float* __restrict__ mom,
        float* __restrict__ out) {
    int t = blockIdx.x * 256 + threadIdx.x;
    int b = t >> 11;                          // 2048 tokens per batch
    const float* M = mom + (size_t)b * 112;
    float a = zq[t];
    float den = 0.f, o0 = 0.f, o1 = 0.f, o2 = 0.f, o3 = 0.f, o4 = 0.f, o5 = 0.f;
    float p = 1.f;
#pragma unroll
    for (int m = 0; m < NMOM; ++m) {
        const float* mm = M + m * 7;
        den += p * mm[0];
        o0 += p * mm[1]; o1 += p * mm[2]; o2 += p * mm[3];
        o3 += p * mm[4]; o4 += p * mm[5]; o5 += p * mm[6];
        p *= a * (1.0f / (m + 1));            // p_{m+1} = p_m * a/(m+1)
    }
    float inv = 1.0f / den;
    float* o = out + (size_t)t * 6;
    float2* o2p = (float2*)o;                 // t*24B is 8-aligned
    o2p[0] = make_float2(o0 * inv, o1 * inv);
    o2p[1] = make_float2(o2 * inv, o3 * inv);
    o2p[2] = make_float2(o4 * inv, o5 * inv);
}

// ---------------------------------------------------------------------------
extern "C" void kernel_launch(void* const* d_in, const int* in_sizes, int n_in,
                              void* d_out, int out_size, void* d_ws, size_t ws_size,
                              hipStream_t stream) {
    const float* x  = (const float*)d_in[0];
    const float* pq = (const float*)d_in[1];
    const float* pk = (const float*)d_in[2];
    const float* pv = (const float*)d_in[3];
    float* w = (float*)d_ws;
    // ws (floats): cs[128] | zq[32768] | kv[262144] | mpart[128*112] | mom[16*112]
    float* cs    = w;
    float* zq    = w + 128;
    float* kv    = w + 128 + NTOK;
    float* mpart = w + 128 + NTOK + NTOK * 8;
    float* mom   = mpart + 128 * 112;
    float* out   = (float*)d_out;

    qsa_prep<<<1, 64, 0, stream>>>(pq, pk, pv, cs);
    qsa_sim<<<dim3(NTOK / 64, 3), 64, 0, stream>>>(x, cs, zq, kv);
    qsa_moments_partial<<<NBATCH * 8, 64, 0, stream>>>(kv, mpart);
    qsa_moments_combine<<<1, 256, 0, stream>>>(mpart, mom);
    qsa_eval<<<NTOK / 256, 256, 0, stream>>>(zq, mom, out);
}